// Round 1
// baseline (1022.936 us; speedup 1.0000x reference)
//
#include <hip/hip_runtime.h>

#define DIM   128
#define DIM4  32          // DIM / 4 float4s per row
#define NGRAPH 4096
#define EPSV  1e-5f

// ---------------------------------------------------------------------------
// Pass 1: one block per graph. segment_ids is sorted, so each graph's nodes
// are contiguous: find [start,end) by binary search, accumulate sum & sumsq
// per dim in registers (float4), LDS-reduce, emit per-(g,d) affine params:
//   A = weight * rsqrt(var + eps),  B = bias - mean*mean_scale*A
// where var = E[x^2] - mean^2 * s * (2 - s)   (exact expansion, one pass)
// ---------------------------------------------------------------------------
__global__ __launch_bounds__(256) void gn_stats(
    const float* __restrict__ feat, const int* __restrict__ seg,
    const float* __restrict__ weight, const float* __restrict__ bias,
    const float* __restrict__ mscale,
    float* __restrict__ A, float* __restrict__ B, int N)
{
    const int g = blockIdx.x;

    // lower_bound(seg, g) and lower_bound(seg, g+1); all threads redundantly
    // (same addresses -> broadcast loads, ~20 iters each)
    int lo = 0, hi = N;
    while (lo < hi) { int mid = (lo + hi) >> 1; if (seg[mid] < g) lo = mid + 1; else hi = mid; }
    const int start = lo;
    hi = N;
    while (lo < hi) { int mid = (lo + hi) >> 1; if (seg[mid] < g + 1) lo = mid + 1; else hi = mid; }
    const int end = lo;

    const int tid  = threadIdx.x;
    const int dim4 = tid & 31;   // which float4 within the 128-dim row
    const int noff = tid >> 5;   // node slice 0..7

    float4 s = make_float4(0.f, 0.f, 0.f, 0.f);
    float4 q = make_float4(0.f, 0.f, 0.f, 0.f);
    for (int n = start + noff; n < end; n += 8) {
        const float4 x = ((const float4*)(feat + (size_t)n * DIM))[dim4];
        s.x += x.x; s.y += x.y; s.z += x.z; s.w += x.w;
        q.x += x.x * x.x; q.y += x.y * x.y; q.z += x.z * x.z; q.w += x.w * x.w;
    }

    __shared__ float4 ls[256];
    __shared__ float4 lq[256];
    ls[tid] = s; lq[tid] = q;
    __syncthreads();
    // reduce the 8 node slices (threads t, t+32, ..., t+224)
    for (int off = 128; off >= 32; off >>= 1) {
        if (tid < off) {
            float4 a = ls[tid], b = ls[tid + off];
            a.x += b.x; a.y += b.y; a.z += b.z; a.w += b.w; ls[tid] = a;
            float4 c = lq[tid], d = lq[tid + off];
            c.x += d.x; c.y += d.y; c.z += d.z; c.w += d.w; lq[tid] = c;
        }
        __syncthreads();
    }

    if (tid < 32) {
        const int   cnt   = (end - start) > 1 ? (end - start) : 1;
        const float inv_c = 1.0f / (float)cnt;
        const float4 S = ls[tid];
        const float4 Q = lq[tid];
#pragma unroll
        for (int j = 0; j < 4; ++j) {
            const int   d   = tid * 4 + j;
            const float Sv  = (&S.x)[j];
            const float Qv  = (&Q.x)[j];
            const float m   = Sv * inv_c;
            const float sc  = mscale[d];
            const float var = Qv * inv_c - m * m * sc * (2.0f - sc);
            const float inv = rsqrtf(var + EPSV);
            const float a   = weight[d] * inv;
            const float b   = bias[d] - m * sc * a;
            A[(size_t)g * DIM + d] = a;
            B[(size_t)g * DIM + d] = b;
        }
    }
}

// ---------------------------------------------------------------------------
// Pass 2 (restructured): one block per graph, same node-range binary search
// as pass 1. Each thread owns (node-slice, dim4) and hoists its A/B float4
// into REGISTERS once per block -> the loop is pure stream:
//   load x (float4) -> 4 fma -> store y (float4).
// Eliminates the per-node A/B gather (~1 GB of L2/L3 traffic) and all seg
// reads of the old apply pass.
// ---------------------------------------------------------------------------
__global__ __launch_bounds__(256) void gn_apply_g(
    const float* __restrict__ feat, const int* __restrict__ seg,
    const float* __restrict__ A, const float* __restrict__ B,
    float* __restrict__ out, int N)
{
    const int g = blockIdx.x;

    int lo = 0, hi = N;
    while (lo < hi) { int mid = (lo + hi) >> 1; if (seg[mid] < g) lo = mid + 1; else hi = mid; }
    const int start = lo;
    hi = N;
    while (lo < hi) { int mid = (lo + hi) >> 1; if (seg[mid] < g + 1) lo = mid + 1; else hi = mid; }
    const int end = lo;
    if (start >= end) return;

    const int tid  = threadIdx.x;
    const int dim4 = tid & 31;
    const int noff = tid >> 5;

    const float4 a = ((const float4*)A)[(size_t)g * DIM4 + dim4];
    const float4 b = ((const float4*)B)[(size_t)g * DIM4 + dim4];

    for (int n = start + noff; n < end; n += 8) {
        const float4 x = ((const float4*)(feat + (size_t)n * DIM))[dim4];
        float4 r;
        r.x = fmaf(x.x, a.x, b.x);
        r.y = fmaf(x.y, a.y, b.y);
        r.z = fmaf(x.z, a.z, b.z);
        r.w = fmaf(x.w, a.w, b.w);
        ((float4*)(out + (size_t)n * DIM))[dim4] = r;
    }
}

extern "C" void kernel_launch(void* const* d_in, const int* in_sizes, int n_in,
                              void* d_out, int out_size, void* d_ws, size_t ws_size,
                              hipStream_t stream) {
    const float* feat   = (const float*)d_in[0];
    const int*   seg    = (const int*)d_in[1];
    // d_in[2] = num_graphs (device scalar) — shape is fixed, use NGRAPH
    const float* weight = (const float*)d_in[3];
    const float* bias   = (const float*)d_in[4];
    const float* mscale = (const float*)d_in[5];
    float*       out    = (float*)d_out;
    const int N = in_sizes[1];

    float* A = (float*)d_ws;                       // NGRAPH*DIM floats
    float* B = A + (size_t)NGRAPH * DIM;           // NGRAPH*DIM floats

    hipLaunchKernelGGL(gn_stats, dim3(NGRAPH), dim3(256), 0, stream,
                       feat, seg, weight, bias, mscale, A, B, N);

    hipLaunchKernelGGL(gn_apply_g, dim3(NGRAPH), dim3(256), 0, stream,
                       feat, seg, A, B, out, N);
}

// Round 2
// 875.712 us; speedup vs baseline: 1.1681x; 1.1681x over previous
//
#include <hip/hip_runtime.h>

#define DIM    128
#define DIM4   32          // DIM/4 float4s per row
#define NGRAPH 4096
#define EPSV   1e-5f
#define STAGE_N 92         // nodes staged in LDS (92*512B = 46 KB)

typedef float f32x4 __attribute__((ext_vector_type(4)));

// ---------------------------------------------------------------------------
// Pass 0: per-graph start offsets from the sorted segment_ids.
// off[g] = lower_bound(seg, g); off[NGRAPH] = N. Handles empty graphs via the
// gap loop (rare: P(empty) ~ e^-244). Replaces 4096 blocks x 2 binary
// searches (~40 dependent ~300cy loads each) with one 4 MB coalesced scan.
// ---------------------------------------------------------------------------
__global__ __launch_bounds__(256) void seg_offsets(
    const int* __restrict__ seg, int* __restrict__ off, int N)
{
    const int i = blockIdx.x * 256 + threadIdx.x;
    if (i >= N) return;
    const int s    = seg[i];
    const int prev = (i == 0) ? -1 : seg[i - 1];
    for (int g = prev + 1; g <= s; ++g) off[g] = i;
    if (i == N - 1) {
        for (int g = s + 1; g <= NGRAPH; ++g) off[g] = N;
    }
}

// ---------------------------------------------------------------------------
// Fused stats + apply: one block (256 thr) per graph.
//  Phase 1: stream the graph's rows once (coalesced float4), accumulate
//           sum/sumsq in registers, stage the first STAGE_N rows in LDS.
//  Reduce:  wave-level pair shuffle + 4-partial LDS tree -> per-dim affine
//           A = weight*rsqrt(var+eps), B = bias - mean*mscale*A, with
//           var = E[x^2] - mean^2*sc*(2-sc)  (one-pass expansion).
//  Phase 2: y = fma(x, A, B); x from LDS stage (first 92 nodes) or from
//           L2/L3 re-read (remainder; reuse window ~15us << L3 turnover).
//           Non-temporal store of out, non-temporal re-read loads.
// LDS: 46 KB stage + 4 KB reduce + 1 KB A/B = 51 KB -> 3 blocks/CU (12 waves).
// ---------------------------------------------------------------------------
__global__ __launch_bounds__(256) void gn_fused(
    const float* __restrict__ feat, const int* __restrict__ off,
    const float* __restrict__ weight, const float* __restrict__ bias,
    const float* __restrict__ mscale, float* __restrict__ out)
{
    const int g     = blockIdx.x;
    const int start = off[g];
    const int end   = off[g + 1];
    const int cnt   = end - start;
    if (cnt <= 0) return;

    const int tid  = threadIdx.x;
    const int dim4 = tid & 31;   // float4 index within 128-dim row
    const int noff = tid >> 5;   // node slice 0..7
    const int wave = tid >> 6;   // 4 waves
    const int lane = tid & 63;

    __shared__ float4 stage[STAGE_N * DIM4];  // 46 KB
    __shared__ float4 red_s[4][32];           // 2 KB
    __shared__ float4 red_q[4][32];           // 2 KB
    __shared__ float4 Ash[32];                // 512 B
    __shared__ float4 Bsh[32];                // 512 B

    // ---- Phase 1: stream + accumulate + stage ----
    float4 s = make_float4(0.f, 0.f, 0.f, 0.f);
    float4 q = make_float4(0.f, 0.f, 0.f, 0.f);
    for (int i = noff; i < cnt; i += 8) {
        const float4 x = ((const float4*)(feat + (size_t)(start + i) * DIM))[dim4];
        s.x += x.x; s.y += x.y; s.z += x.z; s.w += x.w;
        q.x += x.x * x.x; q.y += x.y * x.y; q.z += x.z * x.z; q.w += x.w * x.w;
        if (i < STAGE_N) stage[i * DIM4 + dim4] = x;
    }

    // pair-reduce node slices (2w, 2w+1) within each wave: lane L += lane L+32
    s.x += __shfl_down(s.x, 32); s.y += __shfl_down(s.y, 32);
    s.z += __shfl_down(s.z, 32); s.w += __shfl_down(s.w, 32);
    q.x += __shfl_down(q.x, 32); q.y += __shfl_down(q.y, 32);
    q.z += __shfl_down(q.z, 32); q.w += __shfl_down(q.w, 32);
    if (lane < 32) { red_s[wave][lane] = s; red_q[wave][lane] = q; }
    __syncthreads();

    // ---- final reduce + per-dim affine params ----
    if (tid < 32) {
        float4 S = red_s[0][tid];
        float4 Q = red_q[0][tid];
#pragma unroll
        for (int w = 1; w < 4; ++w) {
            const float4 a = red_s[w][tid];
            S.x += a.x; S.y += a.y; S.z += a.z; S.w += a.w;
            const float4 c = red_q[w][tid];
            Q.x += c.x; Q.y += c.y; Q.z += c.z; Q.w += c.w;
        }
        const float inv_c = 1.0f / (float)cnt;   // cnt >= 1 here
        float4 av, bv;
#pragma unroll
        for (int j = 0; j < 4; ++j) {
            const int   d   = tid * 4 + j;
            const float Sv  = (&S.x)[j];
            const float Qv  = (&Q.x)[j];
            const float m   = Sv * inv_c;
            const float sc  = mscale[d];
            const float var = Qv * inv_c - m * m * sc * (2.0f - sc);
            const float inv = rsqrtf(var + EPSV);
            const float a   = weight[d] * inv;
            const float b   = bias[d] - m * sc * a;
            (&av.x)[j] = a;
            (&bv.x)[j] = b;
        }
        Ash[tid] = av; Bsh[tid] = bv;
    }
    __syncthreads();

    // ---- Phase 2: apply ----
    const float4 a  = Ash[dim4];
    const float4 b  = Bsh[dim4];
    const int    sm = cnt < STAGE_N ? cnt : STAGE_N;

    for (int i = noff; i < cnt; i += 8) {
        float4 x;
        if (i < sm) {
            x = stage[i * DIM4 + dim4];
        } else {
            const f32x4* p = (const f32x4*)(feat + (size_t)(start + i) * DIM) + dim4;
            const f32x4 xv = __builtin_nontemporal_load(p);
            x.x = xv.x; x.y = xv.y; x.z = xv.z; x.w = xv.w;
        }
        f32x4 r;
        r.x = fmaf(x.x, a.x, b.x);
        r.y = fmaf(x.y, a.y, b.y);
        r.z = fmaf(x.z, a.z, b.z);
        r.w = fmaf(x.w, a.w, b.w);
        f32x4* po = (f32x4*)(out + (size_t)(start + i) * DIM) + dim4;
        __builtin_nontemporal_store(r, po);
    }
}

extern "C" void kernel_launch(void* const* d_in, const int* in_sizes, int n_in,
                              void* d_out, int out_size, void* d_ws, size_t ws_size,
                              hipStream_t stream) {
    const float* feat   = (const float*)d_in[0];
    const int*   seg    = (const int*)d_in[1];
    // d_in[2] = num_graphs (device scalar) — shape fixed, use NGRAPH
    const float* weight = (const float*)d_in[3];
    const float* bias   = (const float*)d_in[4];
    const float* mscale = (const float*)d_in[5];
    float*       out    = (float*)d_out;
    const int N = in_sizes[1];

    int* off = (int*)d_ws;                         // (NGRAPH+1) ints

    const int blocks0 = (N + 255) / 256;
    hipLaunchKernelGGL(seg_offsets, dim3(blocks0), dim3(256), 0, stream,
                       seg, off, N);
    hipLaunchKernelGGL(gn_fused, dim3(NGRAPH), dim3(256), 0, stream,
                       feat, off, weight, bias, mscale, out);
}